// Round 11
// baseline (155.439 us; speedup 1.0000x reference)
//
#include <hip/hip_runtime.h>
#include <hip/hip_bf16.h>
#include <math.h>

#define BB 2
#define SS 1024
#define DD 1024
#define HH 16
#define HD 64
#define BH (BB*HH)

typedef __attribute__((ext_vector_type(8))) short short8_t;
typedef __attribute__((ext_vector_type(4))) float f32x4;

#if __has_builtin(__builtin_amdgcn_exp2f)
#define EXP2(x) __builtin_amdgcn_exp2f(x)
#else
#define EXP2(x) exp2f(x)
#endif

__device__ __forceinline__ ushort f2bf(float f) {
    union { float f; unsigned u; } a; a.f = f;
    unsigned u = a.u;
    u += 0x7FFFu + ((u >> 16) & 1u);   // RNE
    return (ushort)(u >> 16);
}
__device__ __forceinline__ float bf2f(ushort b) {
    union { unsigned u; float f; } a; a.u = ((unsigned)b) << 16;
    return a.f;
}
// packed f32x2 -> bf16x2 (RNE), low = a
__device__ __forceinline__ unsigned pkbf(float a, float b) {
    unsigned r;
    asm("v_cvt_pk_bf16_f32 %0, %1, %2" : "=v"(r) : "v"(a), "v"(b));
    return r;
}

// ---------------- fp32 -> bf16 conversion, all 5 tensors in one launch ----------------
__global__ __launch_bounds__(256) void cvt_all_kernel(
    const float* __restrict__ x,  const float* __restrict__ wq,
    const float* __restrict__ wk, const float* __restrict__ wv,
    const float* __restrict__ wo,
    ushort* __restrict__ xb,  ushort* __restrict__ wqb, ushort* __restrict__ wkb,
    ushort* __restrict__ wvb, ushort* __restrict__ wob)
{
    int bid = blockIdx.x;
    const float* src; ushort* dst; int off;
    if (bid < 2048) { src = x; dst = xb; off = bid; }
    else {
        int seg = (bid - 2048) >> 10;
        off = (bid - 2048) & 1023;
        if (seg == 0)      { src = wq; dst = wqb; }
        else if (seg == 1) { src = wk; dst = wkb; }
        else if (seg == 2) { src = wv; dst = wvb; }
        else               { src = wo; dst = wob; }
    }
    int i = (off * 256 + threadIdx.x) * 4;
    float4 v = *reinterpret_cast<const float4*>(src + i);
    ushort4 o;
    o.x = f2bf(v.x); o.y = f2bf(v.y); o.z = f2bf(v.z); o.w = f2bf(v.w);
    *reinterpret_cast<ushort4*>(dst + i) = o;
}

// ---------------- bf16 GEMM (m97 structure): C = A[M,K]*B[N,K]^T, global_load_lds ----------------
template<int BM, int OUT_F32>
__device__ __forceinline__ void gemm_body(
    const ushort* __restrict__ A, const ushort* __restrict__ Bm,
    const float* __restrict__ bias, void* __restrict__ Cout,
    int N, int K, float scale)
{
    constexpr int BK = 32;
    __shared__ ushort lsa[BM * BK];
    __shared__ ushort lsb[128 * BK];
    const int tid  = threadIdx.x;
    const int lane = tid & 63;
    const int wave = tid >> 6;
    constexpr int RI = BM / 32;
    const int wrow = (wave >> 1) * (BM / 2);
    const int wcol = (wave & 1) * 64;
    const int tileM = blockIdx.y * BM;
    const int tileN = blockIdx.x * 128;
    const int fr  = lane & 15;
    const int fks = (lane >> 4) * 8;
    const int l4  = lane >> 2;        // row within 16-row chunk
    const int lm4 = lane & 3;         // 16B slot within 64B row
    f32x4 acc[RI][4] = {};

    for (int kb = 0; kb < K; kb += BK) {
        __syncthreads();
        #pragma unroll
        for (int i = 0; i < BM / 64; ++i) {
            int chunk = wave * (BM / 64) + i;
            const ushort* g = A + (size_t)(tileM + chunk * 16 + l4) * K + kb + lm4 * 8;
            __builtin_amdgcn_global_load_lds(
                (const __attribute__((address_space(1))) unsigned*)g,
                (__attribute__((address_space(3))) unsigned*)&lsa[chunk * 512], 16, 0, 0);
        }
        #pragma unroll
        for (int i = 0; i < 2; ++i) {
            int chunk = wave * 2 + i;
            const ushort* g = Bm + (size_t)(tileN + chunk * 16 + l4) * K + kb + lm4 * 8;
            __builtin_amdgcn_global_load_lds(
                (const __attribute__((address_space(1))) unsigned*)g,
                (__attribute__((address_space(3))) unsigned*)&lsb[chunk * 512], 16, 0, 0);
        }
        __syncthreads();
        short8_t af[RI], bfg[4];
        #pragma unroll
        for (int r = 0; r < RI; ++r)
            af[r] = *reinterpret_cast<const short8_t*>(&lsa[(wrow + r * 16 + fr) * BK + fks]);
        #pragma unroll
        for (int c = 0; c < 4; ++c)
            bfg[c] = *reinterpret_cast<const short8_t*>(&lsb[(wcol + c * 16 + fr) * BK + fks]);
        #pragma unroll
        for (int r = 0; r < RI; ++r)
            #pragma unroll
            for (int c = 0; c < 4; ++c)
                acc[r][c] = __builtin_amdgcn_mfma_f32_16x16x32_bf16(af[r], bfg[c], acc[r][c], 0, 0, 0);
    }

    const int rr = (lane >> 4) * 4;
    #pragma unroll
    for (int r = 0; r < RI; ++r) {
        #pragma unroll
        for (int c = 0; c < 4; ++c) {
            int n = tileN + wcol + c * 16 + fr;
            float bv = bias[n];
            #pragma unroll
            for (int q = 0; q < 4; ++q) {
                int m = tileM + wrow + r * 16 + rr + q;
                float v = (acc[r][c][q] + bv) * scale;
                if (OUT_F32) ((float*)Cout)[(size_t)m * N + n] = v;
                else         ((ushort*)Cout)[(size_t)m * N + n] = f2bf(v);
            }
        }
    }
}

// BM=64 -> grid 768 blocks (3 blocks/CU, balanced; acc=32 regs)
__global__ __launch_bounds__(256) void gemm_qkv_kernel(
    const ushort* __restrict__ xb,
    const ushort* __restrict__ wq, const ushort* __restrict__ wk, const ushort* __restrict__ wv,
    const float* __restrict__ bq, const float* __restrict__ bk, const float* __restrict__ bv,
    ushort* __restrict__ Qb, ushort* __restrict__ Kb, ushort* __restrict__ Vb, float qscale)
{
    const ushort* Bm; const float* bias; ushort* out; float sc;
    if (blockIdx.z == 0)      { Bm = wq; bias = bq; out = Qb; sc = qscale; }
    else if (blockIdx.z == 1) { Bm = wk; bias = bk; out = Kb; sc = 1.0f; }
    else                      { Bm = wv; bias = bv; out = Vb; sc = 1.0f; }
    gemm_body<64, 0>(xb, Bm, bias, out, DD, DD, sc);
}

__global__ __launch_bounds__(256) void gemm_out_kernel(
    const ushort* __restrict__ ctxb, const ushort* __restrict__ wo,
    const float* __restrict__ bo, float* __restrict__ out)
{
    gemm_body<64, 1>(ctxb, wo, bo, out, DD, DD, 1.0f);
}

// ---------------- E tables: E_t[bh,j] = exp(c_t*ph_t*pf[h]*rk[bh,j]) for t=1,3 ----------------
__global__ __launch_bounds__(256) void tables_kernel(const ushort* __restrict__ Kb,
                                                     const float* __restrict__ pf,
                                                     float* __restrict__ E1, float* __restrict__ E3,
                                                     float a1, float a3) {
    int idx = blockIdx.x * blockDim.x + threadIdx.x;  // [0, BH*SS)
    int j  = idx & (SS - 1);
    int bh = idx >> 10;
    int b = bh >> 4, h = bh & 15;
    const ushort* kr = Kb + (size_t)(b * SS + j) * DD + h * HD;
    float s = 0.f;
    #pragma unroll
    for (int c = 0; c < HD; c += 8) {
        short8_t v = *reinterpret_cast<const short8_t*>(kr + c);
        #pragma unroll
        for (int e = 0; e < 8; ++e) s += bf2f((ushort)v[e]);
    }
    float ph = pf[h];
    E1[idx] = __expf(a1 * ph * s);
    E3[idx] = __expf(a3 * ph * s);
}

// ---------------- V transpose: Vt[b,h,d,j] = V[b,j,h*64+d] ----------------
__global__ __launch_bounds__(256) void transpose_v_kernel(const ushort* __restrict__ Vb,
                                                          ushort* __restrict__ Vt) {
    __shared__ ushort t[64][72];
    int bh = blockIdx.x; int b = bh >> 4, h = bh & 15;
    int j0 = blockIdx.y * 64;
    #pragma unroll
    for (int s = 0; s < 2; ++s) {
        int ch = threadIdx.x + s * 256;
        int row = ch >> 3, c = (ch & 7) * 8;
        *reinterpret_cast<short8_t*>(&t[row][c]) =
            *reinterpret_cast<const short8_t*>(Vb + (size_t)(b * SS + j0 + row) * DD + h * HD + c);
    }
    __syncthreads();
    #pragma unroll
    for (int s = 0; s < 2; ++s) {
        int ch = threadIdx.x + s * 256;
        int drow = ch >> 3, c = (ch & 7) * 8;
        short8_t v;
        #pragma unroll
        for (int e = 0; e < 8; ++e) v[e] = (short)t[c + e][drow];
        *reinterpret_cast<short8_t*>(Vt + (size_t)(bh * HD + drow) * SS + j0 + c) = v;
    }
}

// ---------------- two-pass resonance attention, bf16 y-cache + SW pipeline ----------------
// Identical arithmetic to round 10 (validated, absmax 0.0098). Changes are scheduling only:
// pass A unrolled x4 with in-place K reload after QK consumes fragments (loads overlap
// the ~460cyc exp2/powers/ds_write compute); pass B unrolled x4 with V loaded at top.
// Register headroom: round-10 base was 60 VGPR + 16 acc; pipeline adds ~32 in flight
// -> ~110 unified, still within the 128 (4 waves/SIMD) boundary. No launch_bounds
// min-waves (spill trap).
__global__ __launch_bounds__(256) void attn_kernel(
    const ushort* __restrict__ Qb, const ushort* __restrict__ Kb,
    const ushort* __restrict__ Vt, const float* __restrict__ E1,
    const float* __restrict__ E3, ushort* __restrict__ ctxb)
{
    __shared__ ushort ycache[4][16][264];  // per-wave bf16 y cache; reused as f32 ctx partials
    __shared__ float lbuf[4][4][16];       // [wave][t][qrow]
    const int wg  = blockIdx.x;
    const int swz = (wg & 7) * 256 + (wg >> 3);   // XCD swizzle (2048 % 8 == 0)
    const int bh  = swz >> 6;
    const int qt  = swz & 63;
    const int b = bh >> 4, h = bh & 15;
    const int wave = threadIdx.x >> 6;
    const int lane = threadIdx.x & 63;
    const int fr = lane & 15;
    const int g  = lane >> 4;
    const int fk = g * 8;

    const float wt[4] = {0.008f, 0.032f, 0.16f, 0.8f};   // momentum-collapsed weights

    // Q A-fragments (pre-scaled), 16 rows per block
    const ushort* qbase = Qb + (size_t)(b * SS + qt * 16 + fr) * DD + h * HD;
    const short8_t aq0 = *reinterpret_cast<const short8_t*>(qbase + fk);
    const short8_t aq1 = *reinterpret_cast<const short8_t*>(qbase + 32 + fk);

    const float* e1h = E1 + bh * SS;
    const float* e3h = E3 + bh * SS;
    const ushort* kcol = Kb + (size_t)b * SS * DD + h * HD;

    // ---- pass A: QK^T + exp2 + l_t (C-layout) + y -> LDS cache (bf16), pipelined ----
    float lA[4][4] = {};   // [t][r]: partial for q-row g*4+r over k-cols {n*16+fr}
    short8_t nk0[4], nk1[4];
    #pragma unroll
    for (int n = 0; n < 4; ++n) {
        const ushort* kb = kcol + (size_t)(wave * 256 + n * 16 + fr) * DD;
        nk0[n] = *reinterpret_cast<const short8_t*>(kb + fk);
        nk1[n] = *reinterpret_cast<const short8_t*>(kb + 32 + fk);
    }
    #pragma unroll
    for (int it = 0; it < 4; ++it) {
        const int k0 = wave * 256 + it * 64;
        // QK^T on prefetched fragments
        f32x4 accn[4];
        #pragma unroll
        for (int n = 0; n < 4; ++n) {
            f32x4 z = {0.f, 0.f, 0.f, 0.f};
            z = __builtin_amdgcn_mfma_f32_16x16x32_bf16(aq0, nk0[n], z, 0, 0, 0);
            z = __builtin_amdgcn_mfma_f32_16x16x32_bf16(aq1, nk1[n], z, 0, 0, 0);
            accn[n] = z;
        }
        // in-place reload for tile it+1 (fragments consumed by the MFMAs above);
        // overlaps the exp2/powers/ds_write compute below (~460 cyc)
        if (it < 3) {
            #pragma unroll
            for (int n = 0; n < 4; ++n) {
                const ushort* kb = kcol + (size_t)(k0 + 64 + n * 16 + fr) * DD;
                nk0[n] = *reinterpret_cast<const short8_t*>(kb + fk);
                nk1[n] = *reinterpret_cast<const short8_t*>(kb + 32 + fk);
            }
        }
        #pragma unroll
        for (int n = 0; n < 4; ++n) {
            float e1v = e1h[k0 + n * 16 + fr];
            float e3v = e3h[k0 + n * 16 + fr];
            #pragma unroll
            for (int r = 0; r < 4; ++r) {
                float y  = EXP2(accn[n][r]);
                float y2 = y * y;
                float y4 = y2 * y2;
                float y6 = y4 * y2;
                lA[0][r] += y4;
                lA[1][r] += y4 * y * e1v;
                lA[2][r] += y6;
                lA[3][r] += y6 * y * e3v;
                ycache[wave][g * 4 + r][it * 64 + n * 16 + fr] = f2bf(y);
            }
        }
    }
    // reduce across the 16 k-col lanes (lane bits 0..3)
    #pragma unroll
    for (int t = 0; t < 4; ++t)
        #pragma unroll
        for (int r = 0; r < 4; ++r) {
            float s = lA[t][r];
            s += __shfl_xor(s, 1);
            s += __shfl_xor(s, 2);
            s += __shfl_xor(s, 4);
            s += __shfl_xor(s, 8);
            lA[t][r] = s;
        }
    if (fr == 0) {
        #pragma unroll
        for (int t = 0; t < 4; ++t)
            #pragma unroll
            for (int r = 0; r < 4; ++r)
                lbuf[wave][t][g * 4 + r] = lA[t][r];
    }
    __syncthreads();   // orders ycache writes + lbuf for cross-lane pass-B reads

    // per-lane normalized weights for A-frag q-row fr
    float wl0, wl1, wl2, wl3;
    {
        float s0 = lbuf[0][0][fr] + lbuf[1][0][fr] + lbuf[2][0][fr] + lbuf[3][0][fr];
        float s1 = lbuf[0][1][fr] + lbuf[1][1][fr] + lbuf[2][1][fr] + lbuf[3][1][fr];
        float s2 = lbuf[0][2][fr] + lbuf[1][2][fr] + lbuf[2][2][fr] + lbuf[3][2][fr];
        float s3 = lbuf[0][3][fr] + lbuf[1][3][fr] + lbuf[2][3][fr] + lbuf[3][3][fr];
        wl0 = wt[0] / s0; wl1 = wt[1] / s1; wl2 = wt[2] / s2; wl3 = wt[3] / s3;
    }

    // ---- pass B: y-cache read + normalized P + single-accumulator PV, pipelined ----
    f32x4 cacc[4] = {};   // [n2]
    union FragU { short8_t s; unsigned u[4]; };
    #pragma unroll
    for (int it = 0; it < 4; ++it) {
        const int k0 = wave * 256 + it * 64;
        // all 8 V fragments for this tile issued up front (~300cyc before PV use)
        short8_t v0[4], v1[4];
        #pragma unroll
        for (int n2 = 0; n2 < 4; ++n2) {
            const ushort* vb = Vt + (size_t)(bh * HD + n2 * 16 + fr) * SS + k0;
            v0[n2] = *reinterpret_cast<const short8_t*>(vb + fk);
            v1[n2] = *reinterpret_cast<const short8_t*>(vb + 32 + fk);
        }
        #pragma unroll
        for (int half = 0; half < 2; ++half) {
            short8_t yv8 = *reinterpret_cast<const short8_t*>(
                &ycache[wave][fr][it * 64 + half * 32 + fk]);
            const float* e1p = e1h + k0 + half * 32 + fk;
            const float* e3p = e3h + k0 + half * 32 + fk;
            float4 e1a = *reinterpret_cast<const float4*>(e1p);
            float4 e1b = *reinterpret_cast<const float4*>(e1p + 4);
            float4 e3a = *reinterpret_cast<const float4*>(e3p);
            float4 e3b = *reinterpret_cast<const float4*>(e3p + 4);
            FragU pa;
            #pragma unroll
            for (int i = 0; i < 4; ++i) {
                float pv[2];
                #pragma unroll
                for (int j = 0; j < 2; ++j) {
                    const int e = 2 * i + j;
                    float y  = bf2f((ushort)yv8[e]);
                    float y2 = y * y;
                    float y4 = y2 * y2;
                    float e1v = (e < 4) ? ((const float*)&e1a)[e] : ((const float*)&e1b)[e - 4];
                    float e3v = (e < 4) ? ((const float*)&e3a)[e] : ((const float*)&e3b)[e - 4];
                    float t1 = fmaf(y, wl1 * e1v, wl0);
                    float t2 = fmaf(y, wl3 * e3v, wl2);
                    pv[j] = y4 * fmaf(y2, t2, t1);
                }
                pa.u[i] = pkbf(pv[0], pv[1]);
            }
            #pragma unroll
            for (int n2 = 0; n2 < 4; ++n2)
                cacc[n2] = __builtin_amdgcn_mfma_f32_16x16x32_bf16(
                    pa.s, half ? v1[n2] : v0[n2], cacc[n2], 0, 0, 0);
        }
    }

    // ---- epilogue (round-10-validated): per-wave partials -> cross-wave sum ----
    __syncthreads();   // all ycache reads done; safe to reuse as f32
    float* ctxp = (float*)&ycache[wave][0][0];   // [16][68] f32 view (4352B <= 8448B region)
    #pragma unroll
    for (int n2 = 0; n2 < 4; ++n2)
        #pragma unroll
        for (int q = 0; q < 4; ++q)
            ctxp[(g * 4 + q) * 68 + n2 * 16 + fr] = cacc[n2][q];
    __syncthreads();

    const int row = threadIdx.x >> 4;
    const int d0  = (threadIdx.x & 15) * 4;
    float* base = (float*)&ycache[0][0][0];
    float4 s0 = *reinterpret_cast<float4*>(base + 0 * 2112 + row * 68 + d0);
    float4 s1 = *reinterpret_cast<float4*>(base + 1 * 2112 + row * 68 + d0);
    float4 s2 = *reinterpret_cast<float4*>(base + 2 * 2112 + row * 68 + d0);
    float4 s3 = *reinterpret_cast<float4*>(base + 3 * 2112 + row * 68 + d0);
    float ox = s0.x + s1.x + s2.x + s3.x;
    float oy = s0.y + s1.y + s2.y + s3.y;
    float oz = s0.z + s1.z + s2.z + s3.z;
    float ow = s0.w + s1.w + s2.w + s3.w;
    uint2 o;
    o.x = pkbf(ox, oy);
    o.y = pkbf(oz, ow);
    size_t off = (size_t)(b * SS + qt * 16 + row) * DD + h * HD + d0;
    *reinterpret_cast<uint2*>(ctxb + off) = o;
}

// ---------------- launch ----------------
extern "C" void kernel_launch(void* const* d_in, const int* in_sizes, int n_in,
                              void* d_out, int out_size, void* d_ws, size_t ws_size,
                              hipStream_t stream) {
    const float* x  = (const float*)d_in[0];
    const float* Wq = (const float*)d_in[1];
    const float* bq = (const float*)d_in[2];
    const float* Wk = (const float*)d_in[3];
    const float* bk = (const float*)d_in[4];
    const float* Wv = (const float*)d_in[5];
    const float* bv = (const float*)d_in[6];
    const float* Wo = (const float*)d_in[7];
    const float* bo = (const float*)d_in[8];
    // d_in[9] resonance_bias: per-head row-constant -> cancels in softmax
    const float* pf = (const float*)d_in[10];

    // workspace layout (~32.3 MB)
    ushort* xb   = (ushort*)d_ws;
    ushort* wqb  = xb  + (size_t)2 * 1024 * 1024;
    ushort* wkb  = wqb + (size_t)1024 * 1024;
    ushort* wvb  = wkb + (size_t)1024 * 1024;
    ushort* wob  = wvb + (size_t)1024 * 1024;
    ushort* Qb   = wob + (size_t)1024 * 1024;
    ushort* Kb   = Qb  + (size_t)2 * 1024 * 1024;
    ushort* Vb   = Kb  + (size_t)2 * 1024 * 1024;
    ushort* Vt   = Vb  + (size_t)2 * 1024 * 1024;
    ushort* ctxb = Vt  + (size_t)2 * 1024 * 1024;
    float*  E1p  = (float*)(ctxb + (size_t)2 * 1024 * 1024);
    float*  E3p  = E1p + (size_t)BH * SS;

    // per-iteration constants (match reference f32 casting)
    float ph[4], ctv[4];
    for (int t = 0; t < 4; ++t) {
        double tn = (double)t / 4.0;
        ph[t]  = sinf((float)(2.0 * tn * M_PI + 0.0));
        ctv[t] = (float)((0.8 + 0.2 * (double)t) * 0.125);  // beta_t / sqrt(HD)
    }
    const double LOG2E = 1.44269504088896340736;
    float qscale = (float)(0.025 * LOG2E);  // Q pre-scale: S' = 0.025*log2e*S
    float a1 = ctv[1] * ph[1];   // c1 * sin(pi/2)
    float a3 = ctv[3] * ph[3];   // c3 * sin(3pi/2)

    cvt_all_kernel<<<6144, 256, 0, stream>>>(x, Wq, Wk, Wv, Wo, xb, wqb, wkb, wvb, wob);

    gemm_qkv_kernel<<<dim3(8, 32, 3), 256, 0, stream>>>(xb, wqb, wkb, wvb, bq, bk, bv,
                                                        Qb, Kb, Vb, qscale);

    tables_kernel<<<BH * SS / 256, 256, 0, stream>>>(Kb, pf, E1p, E3p, a1, a3);
    transpose_v_kernel<<<dim3(BH, SS / 64), 256, 0, stream>>>(Vb, Vt);

    attn_kernel<<<2048, 256, 0, stream>>>(Qb, Kb, Vt, E1p, E3p, ctxb);

    gemm_out_kernel<<<dim3(8, 32), 256, 0, stream>>>(ctxb, wob, bo, (float*)d_out);
}

// Round 12
// 132.607 us; speedup vs baseline: 1.1722x; 1.1722x over previous
//
#include <hip/hip_runtime.h>
#include <hip/hip_bf16.h>
#include <math.h>

#define BB 2
#define SS 1024
#define DD 1024
#define HH 16
#define HD 64
#define BH (BB*HH)

typedef __attribute__((ext_vector_type(8))) short short8_t;
typedef __attribute__((ext_vector_type(4))) float f32x4;

#if __has_builtin(__builtin_amdgcn_exp2f)
#define EXP2(x) __builtin_amdgcn_exp2f(x)
#else
#define EXP2(x) exp2f(x)
#endif

__device__ __forceinline__ ushort f2bf(float f) {
    union { float f; unsigned u; } a; a.f = f;
    unsigned u = a.u;
    u += 0x7FFFu + ((u >> 16) & 1u);   // RNE
    return (ushort)(u >> 16);
}
__device__ __forceinline__ float bf2f(ushort b) {
    union { unsigned u; float f; } a; a.u = ((unsigned)b) << 16;
    return a.f;
}
// packed f32x2 -> bf16x2 (RNE), low = a
__device__ __forceinline__ unsigned pkbf(float a, float b) {
    unsigned r;
    asm("v_cvt_pk_bf16_f32 %0, %1, %2" : "=v"(r) : "v"(a), "v"(b));
    return r;
}

// ---------------- fp32 -> bf16 conversion, all 5 tensors in one launch ----------------
__global__ __launch_bounds__(256) void cvt_all_kernel(
    const float* __restrict__ x,  const float* __restrict__ wq,
    const float* __restrict__ wk, const float* __restrict__ wv,
    const float* __restrict__ wo,
    ushort* __restrict__ xb,  ushort* __restrict__ wqb, ushort* __restrict__ wkb,
    ushort* __restrict__ wvb, ushort* __restrict__ wob)
{
    int bid = blockIdx.x;
    const float* src; ushort* dst; int off;
    if (bid < 2048) { src = x; dst = xb; off = bid; }
    else {
        int seg = (bid - 2048) >> 10;
        off = (bid - 2048) & 1023;
        if (seg == 0)      { src = wq; dst = wqb; }
        else if (seg == 1) { src = wk; dst = wkb; }
        else if (seg == 2) { src = wv; dst = wvb; }
        else               { src = wo; dst = wob; }
    }
    int i = (off * 256 + threadIdx.x) * 4;
    float4 v = *reinterpret_cast<const float4*>(src + i);
    ushort4 o;
    o.x = f2bf(v.x); o.y = f2bf(v.y); o.z = f2bf(v.z); o.w = f2bf(v.w);
    *reinterpret_cast<ushort4*>(dst + i) = o;
}

// ---------------- bf16 GEMM (m97 structure): C = A[M,K]*B[N,K]^T, global_load_lds ----------------
template<int BM, int OUT_F32>
__device__ __forceinline__ void gemm_body(
    const ushort* __restrict__ A, const ushort* __restrict__ Bm,
    const float* __restrict__ bias, void* __restrict__ Cout,
    int N, int K, float scale)
{
    constexpr int BK = 32;
    __shared__ ushort lsa[BM * BK];
    __shared__ ushort lsb[128 * BK];
    const int tid  = threadIdx.x;
    const int lane = tid & 63;
    const int wave = tid >> 6;
    constexpr int RI = BM / 32;
    const int wrow = (wave >> 1) * (BM / 2);
    const int wcol = (wave & 1) * 64;
    const int tileM = blockIdx.y * BM;
    const int tileN = blockIdx.x * 128;
    const int fr  = lane & 15;
    const int fks = (lane >> 4) * 8;
    const int l4  = lane >> 2;        // row within 16-row chunk
    const int lm4 = lane & 3;         // 16B slot within 64B row
    f32x4 acc[RI][4] = {};

    for (int kb = 0; kb < K; kb += BK) {
        __syncthreads();
        #pragma unroll
        for (int i = 0; i < BM / 64; ++i) {
            int chunk = wave * (BM / 64) + i;
            const ushort* g = A + (size_t)(tileM + chunk * 16 + l4) * K + kb + lm4 * 8;
            __builtin_amdgcn_global_load_lds(
                (const __attribute__((address_space(1))) unsigned*)g,
                (__attribute__((address_space(3))) unsigned*)&lsa[chunk * 512], 16, 0, 0);
        }
        #pragma unroll
        for (int i = 0; i < 2; ++i) {
            int chunk = wave * 2 + i;
            const ushort* g = Bm + (size_t)(tileN + chunk * 16 + l4) * K + kb + lm4 * 8;
            __builtin_amdgcn_global_load_lds(
                (const __attribute__((address_space(1))) unsigned*)g,
                (__attribute__((address_space(3))) unsigned*)&lsb[chunk * 512], 16, 0, 0);
        }
        __syncthreads();
        short8_t af[RI], bfg[4];
        #pragma unroll
        for (int r = 0; r < RI; ++r)
            af[r] = *reinterpret_cast<const short8_t*>(&lsa[(wrow + r * 16 + fr) * BK + fks]);
        #pragma unroll
        for (int c = 0; c < 4; ++c)
            bfg[c] = *reinterpret_cast<const short8_t*>(&lsb[(wcol + c * 16 + fr) * BK + fks]);
        #pragma unroll
        for (int r = 0; r < RI; ++r)
            #pragma unroll
            for (int c = 0; c < 4; ++c)
                acc[r][c] = __builtin_amdgcn_mfma_f32_16x16x32_bf16(af[r], bfg[c], acc[r][c], 0, 0, 0);
    }

    const int rr = (lane >> 4) * 4;
    #pragma unroll
    for (int r = 0; r < RI; ++r) {
        #pragma unroll
        for (int c = 0; c < 4; ++c) {
            int n = tileN + wcol + c * 16 + fr;
            float bv = bias[n];
            #pragma unroll
            for (int q = 0; q < 4; ++q) {
                int m = tileM + wrow + r * 16 + rr + q;
                float v = (acc[r][c][q] + bv) * scale;
                if (OUT_F32) ((float*)Cout)[(size_t)m * N + n] = v;
                else         ((ushort*)Cout)[(size_t)m * N + n] = f2bf(v);
            }
        }
    }
}

__global__ __launch_bounds__(256) void gemm_qkv_kernel(
    const ushort* __restrict__ xb,
    const ushort* __restrict__ wq, const ushort* __restrict__ wk, const ushort* __restrict__ wv,
    const float* __restrict__ bq, const float* __restrict__ bk, const float* __restrict__ bv,
    ushort* __restrict__ Qb, ushort* __restrict__ Kb, ushort* __restrict__ Vb, float qscale)
{
    const ushort* Bm; const float* bias; ushort* out; float sc;
    if (blockIdx.z == 0)      { Bm = wq; bias = bq; out = Qb; sc = qscale; }
    else if (blockIdx.z == 1) { Bm = wk; bias = bk; out = Kb; sc = 1.0f; }
    else                      { Bm = wv; bias = bv; out = Vb; sc = 1.0f; }
    gemm_body<128, 0>(xb, Bm, bias, out, DD, DD, sc);
}

__global__ __launch_bounds__(256) void gemm_out_kernel(
    const ushort* __restrict__ ctxb, const ushort* __restrict__ wo,
    const float* __restrict__ bo, float* __restrict__ out)
{
    gemm_body<64, 1>(ctxb, wo, bo, out, DD, DD, 1.0f);
}

// ---------------- E tables: E_t[bh,j] = exp(c_t*ph_t*pf[h]*rk[bh,j]) for t=1,3 ----------------
__global__ __launch_bounds__(256) void tables_kernel(const ushort* __restrict__ Kb,
                                                     const float* __restrict__ pf,
                                                     float* __restrict__ E1, float* __restrict__ E3,
                                                     float a1, float a3) {
    int idx = blockIdx.x * blockDim.x + threadIdx.x;  // [0, BH*SS)
    int j  = idx & (SS - 1);
    int bh = idx >> 10;
    int b = bh >> 4, h = bh & 15;
    const ushort* kr = Kb + (size_t)(b * SS + j) * DD + h * HD;
    float s = 0.f;
    #pragma unroll
    for (int c = 0; c < HD; c += 8) {
        short8_t v = *reinterpret_cast<const short8_t*>(kr + c);
        #pragma unroll
        for (int e = 0; e < 8; ++e) s += bf2f((ushort)v[e]);
    }
    float ph = pf[h];
    E1[idx] = __expf(a1 * ph * s);
    E3[idx] = __expf(a3 * ph * s);
}

// ---------------- V transpose: Vt[b,h,d,j] = V[b,j,h*64+d] ----------------
__global__ __launch_bounds__(256) void transpose_v_kernel(const ushort* __restrict__ Vb,
                                                          ushort* __restrict__ Vt) {
    __shared__ ushort t[64][72];
    int bh = blockIdx.x; int b = bh >> 4, h = bh & 15;
    int j0 = blockIdx.y * 64;
    #pragma unroll
    for (int s = 0; s < 2; ++s) {
        int ch = threadIdx.x + s * 256;
        int row = ch >> 3, c = (ch & 7) * 8;
        *reinterpret_cast<short8_t*>(&t[row][c]) =
            *reinterpret_cast<const short8_t*>(Vb + (size_t)(b * SS + j0 + row) * DD + h * HD + c);
    }
    __syncthreads();
    #pragma unroll
    for (int s = 0; s < 2; ++s) {
        int ch = threadIdx.x + s * 256;
        int drow = ch >> 3, c = (ch & 7) * 8;
        short8_t v;
        #pragma unroll
        for (int e = 0; e < 8; ++e) v[e] = (short)t[c + e][drow];
        *reinterpret_cast<short8_t*>(Vt + (size_t)(bh * HD + drow) * SS + j0 + c) = v;
    }
}

// ---------------- two-pass resonance attention, bf16 y-cache, 128-k chain steps ----------------
// Identical arithmetic to round 10 (validated, absmax 0.0098). Change: both passes use
// 128-k tiles (pass A: 2 iters x 8 n-subtiles; pass B: 2 iters x 4 halves) — halves the
// number of serial chain steps per wave and doubles the independent load->MFMA->exp
// chains visible per step. accn[8] transient (+16 regs over R10 base 60+16). No
// launch_bounds min-waves (spill trap); tripwire: WRITE_SIZE must stay ~4MB.
__global__ __launch_bounds__(256) void attn_kernel(
    const ushort* __restrict__ Qb, const ushort* __restrict__ Kb,
    const ushort* __restrict__ Vt, const float* __restrict__ E1,
    const float* __restrict__ E3, ushort* __restrict__ ctxb)
{
    __shared__ ushort ycache[4][16][264];  // per-wave bf16 y cache; reused as f32 ctx partials
    __shared__ float lbuf[4][4][16];       // [wave][t][qrow]
    const int wg  = blockIdx.x;
    const int swz = (wg & 7) * 256 + (wg >> 3);   // XCD swizzle (2048 % 8 == 0)
    const int bh  = swz >> 6;
    const int qt  = swz & 63;
    const int b = bh >> 4, h = bh & 15;
    const int wave = threadIdx.x >> 6;
    const int lane = threadIdx.x & 63;
    const int fr = lane & 15;
    const int g  = lane >> 4;
    const int fk = g * 8;

    const float wt[4] = {0.008f, 0.032f, 0.16f, 0.8f};   // momentum-collapsed weights

    // Q A-fragments (pre-scaled), 16 rows per block
    const ushort* qbase = Qb + (size_t)(b * SS + qt * 16 + fr) * DD + h * HD;
    const short8_t aq0 = *reinterpret_cast<const short8_t*>(qbase + fk);
    const short8_t aq1 = *reinterpret_cast<const short8_t*>(qbase + 32 + fk);

    const float* e1h = E1 + bh * SS;
    const float* e3h = E3 + bh * SS;
    const ushort* kcol = Kb + (size_t)b * SS * DD + h * HD;

    // ---- pass A: QK^T + exp2 + l_t (C-layout) + y -> LDS cache (bf16), 2x128-k steps ----
    float lA[4][4] = {};   // [t][r]: partial for q-row g*4+r over k-cols {n*16+fr}
    #pragma unroll
    for (int it = 0; it < 2; ++it) {
        const int k0 = wave * 256 + it * 128;
        f32x4 accn[8];
        #pragma unroll
        for (int n = 0; n < 8; ++n) {
            const ushort* kb = kcol + (size_t)(k0 + n * 16 + fr) * DD;
            short8_t bk0 = *reinterpret_cast<const short8_t*>(kb + fk);
            short8_t bk1 = *reinterpret_cast<const short8_t*>(kb + 32 + fk);
            f32x4 z = {0.f, 0.f, 0.f, 0.f};
            z = __builtin_amdgcn_mfma_f32_16x16x32_bf16(aq0, bk0, z, 0, 0, 0);
            z = __builtin_amdgcn_mfma_f32_16x16x32_bf16(aq1, bk1, z, 0, 0, 0);
            accn[n] = z;
        }
        #pragma unroll
        for (int n = 0; n < 8; ++n) {
            float e1v = e1h[k0 + n * 16 + fr];
            float e3v = e3h[k0 + n * 16 + fr];
            #pragma unroll
            for (int r = 0; r < 4; ++r) {
                float y  = EXP2(accn[n][r]);
                float y2 = y * y;
                float y4 = y2 * y2;
                float y6 = y4 * y2;
                lA[0][r] += y4;
                lA[1][r] += y4 * y * e1v;
                lA[2][r] += y6;
                lA[3][r] += y6 * y * e3v;
                ycache[wave][g * 4 + r][it * 128 + n * 16 + fr] = f2bf(y);
            }
        }
    }
    // reduce across the 16 k-col lanes (lane bits 0..3)
    #pragma unroll
    for (int t = 0; t < 4; ++t)
        #pragma unroll
        for (int r = 0; r < 4; ++r) {
            float s = lA[t][r];
            s += __shfl_xor(s, 1);
            s += __shfl_xor(s, 2);
            s += __shfl_xor(s, 4);
            s += __shfl_xor(s, 8);
            lA[t][r] = s;
        }
    if (fr == 0) {
        #pragma unroll
        for (int t = 0; t < 4; ++t)
            #pragma unroll
            for (int r = 0; r < 4; ++r)
                lbuf[wave][t][g * 4 + r] = lA[t][r];
    }
    __syncthreads();   // orders ycache writes + lbuf for cross-lane pass-B reads

    // per-lane normalized weights for A-frag q-row fr
    float wl0, wl1, wl2, wl3;
    {
        float s0 = lbuf[0][0][fr] + lbuf[1][0][fr] + lbuf[2][0][fr] + lbuf[3][0][fr];
        float s1 = lbuf[0][1][fr] + lbuf[1][1][fr] + lbuf[2][1][fr] + lbuf[3][1][fr];
        float s2 = lbuf[0][2][fr] + lbuf[1][2][fr] + lbuf[2][2][fr] + lbuf[3][2][fr];
        float s3 = lbuf[0][3][fr] + lbuf[1][3][fr] + lbuf[2][3][fr] + lbuf[3][3][fr];
        wl0 = wt[0] / s0; wl1 = wt[1] / s1; wl2 = wt[2] / s2; wl3 = wt[3] / s3;
    }

    // ---- pass B: y-cache read + normalized P + single-accumulator PV, 2x128-k steps ----
    f32x4 cacc[4] = {};   // [n2]
    union FragU { short8_t s; unsigned u[4]; };
    #pragma unroll
    for (int it = 0; it < 2; ++it) {
        const int k0 = wave * 256 + it * 128;
        #pragma unroll
        for (int half = 0; half < 4; ++half) {
            short8_t yv8 = *reinterpret_cast<const short8_t*>(
                &ycache[wave][fr][it * 128 + half * 32 + fk]);
            const float* e1p = e1h + k0 + half * 32 + fk;
            const float* e3p = e3h + k0 + half * 32 + fk;
            float4 e1a = *reinterpret_cast<const float4*>(e1p);
            float4 e1b = *reinterpret_cast<const float4*>(e1p + 4);
            float4 e3a = *reinterpret_cast<const float4*>(e3p);
            float4 e3b = *reinterpret_cast<const float4*>(e3p + 4);
            FragU pa;
            #pragma unroll
            for (int i = 0; i < 4; ++i) {
                float pv[2];
                #pragma unroll
                for (int j = 0; j < 2; ++j) {
                    const int e = 2 * i + j;
                    float y  = bf2f((ushort)yv8[e]);
                    float y2 = y * y;
                    float y4 = y2 * y2;
                    float e1v = (e < 4) ? ((const float*)&e1a)[e] : ((const float*)&e1b)[e - 4];
                    float e3v = (e < 4) ? ((const float*)&e3a)[e] : ((const float*)&e3b)[e - 4];
                    float t1 = fmaf(y, wl1 * e1v, wl0);
                    float t2 = fmaf(y, wl3 * e3v, wl2);
                    pv[j] = y4 * fmaf(y2, t2, t1);
                }
                pa.u[i] = pkbf(pv[0], pv[1]);
            }
            #pragma unroll
            for (int n2 = 0; n2 < 4; ++n2) {
                const ushort* vb = Vt + (size_t)(bh * HD + n2 * 16 + fr) * SS + k0 + half * 32;
                short8_t v = *reinterpret_cast<const short8_t*>(vb + fk);
                cacc[n2] = __builtin_amdgcn_mfma_f32_16x16x32_bf16(pa.s, v, cacc[n2], 0, 0, 0);
            }
        }
    }

    // ---- epilogue (round-10-validated): per-wave partials -> cross-wave sum ----
    __syncthreads();   // all ycache reads done; safe to reuse as f32
    float* ctxp = (float*)&ycache[wave][0][0];   // [16][68] f32 view (4352B <= 8448B region)
    #pragma unroll
    for (int n2 = 0; n2 < 4; ++n2)
        #pragma unroll
        for (int q = 0; q < 4; ++q)
            ctxp[(g * 4 + q) * 68 + n2 * 16 + fr] = cacc[n2][q];
    __syncthreads();

    const int row = threadIdx.x >> 4;
    const int d0  = (threadIdx.x & 15) * 4;
    float* base = (float*)&ycache[0][0][0];
    float4 s0 = *reinterpret_cast<float4*>(base + 0 * 2112 + row * 68 + d0);
    float4 s1 = *reinterpret_cast<float4*>(base + 1 * 2112 + row * 68 + d0);
    float4 s2 = *reinterpret_cast<float4*>(base + 2 * 2112 + row * 68 + d0);
    float4 s3 = *reinterpret_cast<float4*>(base + 3 * 2112 + row * 68 + d0);
    float ox = s0.x + s1.x + s2.x + s3.x;
    float oy = s0.y + s1.y + s2.y + s3.y;
    float oz = s0.z + s1.z + s2.z + s3.z;
    float ow = s0.w + s1.w + s2.w + s3.w;
    uint2 o;
    o.x = pkbf(ox, oy);
    o.y = pkbf(oz, ow);
    size_t off = (size_t)(b * SS + qt * 16 + row) * DD + h * HD + d0;
    *reinterpret_cast<uint2*>(ctxb + off) = o;
}

// ---------------- launch ----------------
extern "C" void kernel_launch(void* const* d_in, const int* in_sizes, int n_in,
                              void* d_out, int out_size, void* d_ws, size_t ws_size,
                              hipStream_t stream) {
    const float* x  = (const float*)d_in[0];
    const float* Wq = (const float*)d_in[1];
    const float* bq = (const float*)d_in[2];
    const float* Wk = (const float*)d_in[3];
    const float* bk = (const float*)d_in[4];
    const float* Wv = (const float*)d_in[5];
    const float* bv = (const float*)d_in[6];
    const float* Wo = (const float*)d_in[7];
    const float* bo = (const float*)d_in[8];
    // d_in[9] resonance_bias: per-head row-constant -> cancels in softmax
    const float* pf = (const float*)d_in[10];

    // workspace layout (~32.3 MB)
    ushort* xb   = (ushort*)d_ws;
    ushort* wqb  = xb  + (size_t)2 * 1024 * 1024;
    ushort* wkb  = wqb + (size_t)1024 * 1024;
    ushort* wvb  = wkb + (size_t)1024 * 1024;
    ushort* wob  = wvb + (size_t)1024 * 1024;
    ushort* Qb   = wob + (size_t)1024 * 1024;
    ushort* Kb   = Qb  + (size_t)2 * 1024 * 1024;
    ushort* Vb   = Kb  + (size_t)2 * 1024 * 1024;
    ushort* Vt   = Vb  + (size_t)2 * 1024 * 1024;
    ushort* ctxb = Vt  + (size_t)2 * 1024 * 1024;
    float*  E1p  = (float*)(ctxb + (size_t)2 * 1024 * 1024);
    float*  E3p  = E1p + (size_t)BH * SS;

    // per-iteration constants (match reference f32 casting)
    float ph[4], ctv[4];
    for (int t = 0; t < 4; ++t) {
        double tn = (double)t / 4.0;
        ph[t]  = sinf((float)(2.0 * tn * M_PI + 0.0));
        ctv[t] = (float)((0.8 + 0.2 * (double)t) * 0.125);  // beta_t / sqrt(HD)
    }
    const double LOG2E = 1.44269504088896340736;
    float qscale = (float)(0.025 * LOG2E);  // Q pre-scale: S' = 0.025*log2e*S
    float a1 = ctv[1] * ph[1];   // c1 * sin(pi/2)
    float a3 = ctv[3] * ph[3];   // c3 * sin(3pi/2)

    cvt_all_kernel<<<6144, 256, 0, stream>>>(x, Wq, Wk, Wv, Wo, xb, wqb, wkb, wvb, wob);

    gemm_qkv_kernel<<<dim3(8, 16, 3), 256, 0, stream>>>(xb, wqb, wkb, wvb, bq, bk, bv,
                                                        Qb, Kb, Vb, qscale);

    tables_kernel<<<BH * SS / 256, 256, 0, stream>>>(Kb, pf, E1p, E3p, a1, a3);
    transpose_v_kernel<<<dim3(BH, SS / 64), 256, 0, stream>>>(Vb, Vt);

    attn_kernel<<<2048, 256, 0, stream>>>(Qb, Kb, Vt, E1p, E3p, ctxb);

    gemm_out_kernel<<<dim3(8, 32), 256, 0, stream>>>(ctxb, wob, bo, (float*)d_out);
}

// Round 13
// 111.566 us; speedup vs baseline: 1.3932x; 1.1886x over previous
//
#include <hip/hip_runtime.h>
#include <hip/hip_bf16.h>
#include <math.h>

#define BB 2
#define SS 1024
#define DD 1024
#define HH 16
#define HD 64
#define BH (BB*HH)

typedef __attribute__((ext_vector_type(8))) short short8_t;
typedef __attribute__((ext_vector_type(4))) float f32x4;

#if __has_builtin(__builtin_amdgcn_exp2f)
#define EXP2(x) __builtin_amdgcn_exp2f(x)
#else
#define EXP2(x) exp2f(x)
#endif

__device__ __forceinline__ ushort f2bf(float f) {
    union { float f; unsigned u; } a; a.f = f;
    unsigned u = a.u;
    u += 0x7FFFu + ((u >> 16) & 1u);   // RNE
    return (ushort)(u >> 16);
}
__device__ __forceinline__ float bf2f(ushort b) {
    union { unsigned u; float f; } a; a.u = ((unsigned)b) << 16;
    return a.f;
}
// packed f32x2 -> bf16x2 (RNE), low = a
__device__ __forceinline__ unsigned pkbf(float a, float b) {
    unsigned r;
    asm("v_cvt_pk_bf16_f32 %0, %1, %2" : "=v"(r) : "v"(a), "v"(b));
    return r;
}

// ---------------- fp32 -> bf16 conversion, all 5 tensors in one launch ----------------
__global__ __launch_bounds__(256) void cvt_all_kernel(
    const float* __restrict__ x,  const float* __restrict__ wq,
    const float* __restrict__ wk, const float* __restrict__ wv,
    const float* __restrict__ wo,
    ushort* __restrict__ xb,  ushort* __restrict__ wqb, ushort* __restrict__ wkb,
    ushort* __restrict__ wvb, ushort* __restrict__ wob)
{
    int bid = blockIdx.x;
    const float* src; ushort* dst; int off;
    if (bid < 2048) { src = x; dst = xb; off = bid; }
    else {
        int seg = (bid - 2048) >> 10;
        off = (bid - 2048) & 1023;
        if (seg == 0)      { src = wq; dst = wqb; }
        else if (seg == 1) { src = wk; dst = wkb; }
        else if (seg == 2) { src = wv; dst = wvb; }
        else               { src = wo; dst = wob; }
    }
    int i = (off * 256 + threadIdx.x) * 4;
    float4 v = *reinterpret_cast<const float4*>(src + i);
    ushort4 o;
    o.x = f2bf(v.x); o.y = f2bf(v.y); o.z = f2bf(v.z); o.w = f2bf(v.w);
    *reinterpret_cast<ushort4*>(dst + i) = o;
}

// ---------------- bf16 GEMM (m97 structure): C = A[M,K]*B[N,K]^T, global_load_lds ----------------
template<int BM, int OUT_F32>
__device__ __forceinline__ void gemm_body(
    const ushort* __restrict__ A, const ushort* __restrict__ Bm,
    const float* __restrict__ bias, void* __restrict__ Cout,
    int N, int K, float scale)
{
    constexpr int BK = 32;
    __shared__ ushort lsa[BM * BK];
    __shared__ ushort lsb[128 * BK];
    const int tid  = threadIdx.x;
    const int lane = tid & 63;
    const int wave = tid >> 6;
    constexpr int RI = BM / 32;
    const int wrow = (wave >> 1) * (BM / 2);
    const int wcol = (wave & 1) * 64;
    const int tileM = blockIdx.y * BM;
    const int tileN = blockIdx.x * 128;
    const int fr  = lane & 15;
    const int fks = (lane >> 4) * 8;
    const int l4  = lane >> 2;        // row within 16-row chunk
    const int lm4 = lane & 3;         // 16B slot within 64B row
    f32x4 acc[RI][4] = {};

    for (int kb = 0; kb < K; kb += BK) {
        __syncthreads();
        #pragma unroll
        for (int i = 0; i < BM / 64; ++i) {
            int chunk = wave * (BM / 64) + i;
            const ushort* g = A + (size_t)(tileM + chunk * 16 + l4) * K + kb + lm4 * 8;
            __builtin_amdgcn_global_load_lds(
                (const __attribute__((address_space(1))) unsigned*)g,
                (__attribute__((address_space(3))) unsigned*)&lsa[chunk * 512], 16, 0, 0);
        }
        #pragma unroll
        for (int i = 0; i < 2; ++i) {
            int chunk = wave * 2 + i;
            const ushort* g = Bm + (size_t)(tileN + chunk * 16 + l4) * K + kb + lm4 * 8;
            __builtin_amdgcn_global_load_lds(
                (const __attribute__((address_space(1))) unsigned*)g,
                (__attribute__((address_space(3))) unsigned*)&lsb[chunk * 512], 16, 0, 0);
        }
        __syncthreads();
        short8_t af[RI], bfg[4];
        #pragma unroll
        for (int r = 0; r < RI; ++r)
            af[r] = *reinterpret_cast<const short8_t*>(&lsa[(wrow + r * 16 + fr) * BK + fks]);
        #pragma unroll
        for (int c = 0; c < 4; ++c)
            bfg[c] = *reinterpret_cast<const short8_t*>(&lsb[(wcol + c * 16 + fr) * BK + fks]);
        #pragma unroll
        for (int r = 0; r < RI; ++r)
            #pragma unroll
            for (int c = 0; c < 4; ++c)
                acc[r][c] = __builtin_amdgcn_mfma_f32_16x16x32_bf16(af[r], bfg[c], acc[r][c], 0, 0, 0);
    }

    const int rr = (lane >> 4) * 4;
    #pragma unroll
    for (int r = 0; r < RI; ++r) {
        #pragma unroll
        for (int c = 0; c < 4; ++c) {
            int n = tileN + wcol + c * 16 + fr;
            float bv = bias[n];
            #pragma unroll
            for (int q = 0; q < 4; ++q) {
                int m = tileM + wrow + r * 16 + rr + q;
                float v = (acc[r][c][q] + bv) * scale;
                if (OUT_F32) ((float*)Cout)[(size_t)m * N + n] = v;
                else         ((ushort*)Cout)[(size_t)m * N + n] = f2bf(v);
            }
        }
    }
}

__global__ __launch_bounds__(256) void gemm_qkv_kernel(
    const ushort* __restrict__ xb,
    const ushort* __restrict__ wq, const ushort* __restrict__ wk, const ushort* __restrict__ wv,
    const float* __restrict__ bq, const float* __restrict__ bk, const float* __restrict__ bv,
    ushort* __restrict__ Qb, ushort* __restrict__ Kb, ushort* __restrict__ Vb, float qscale)
{
    const ushort* Bm; const float* bias; ushort* out; float sc;
    if (blockIdx.z == 0)      { Bm = wq; bias = bq; out = Qb; sc = qscale; }
    else if (blockIdx.z == 1) { Bm = wk; bias = bk; out = Kb; sc = 1.0f; }
    else                      { Bm = wv; bias = bv; out = Vb; sc = 1.0f; }
    gemm_body<128, 0>(xb, Bm, bias, out, DD, DD, sc);
}

__global__ __launch_bounds__(256) void gemm_out_kernel(
    const ushort* __restrict__ ctxb, const ushort* __restrict__ wo,
    const float* __restrict__ bo, float* __restrict__ out)
{
    gemm_body<64, 1>(ctxb, wo, bo, out, DD, DD, 1.0f);
}

// ---------------- E tables: E_t[bh,j] = exp(c_t*ph_t*pf[h]*rk[bh,j]) for t=1,3 ----------------
__global__ __launch_bounds__(256) void tables_kernel(const ushort* __restrict__ Kb,
                                                     const float* __restrict__ pf,
                                                     float* __restrict__ E1, float* __restrict__ E3,
                                                     float a1, float a3) {
    int idx = blockIdx.x * blockDim.x + threadIdx.x;  // [0, BH*SS)
    int j  = idx & (SS - 1);
    int bh = idx >> 10;
    int b = bh >> 4, h = bh & 15;
    const ushort* kr = Kb + (size_t)(b * SS + j) * DD + h * HD;
    float s = 0.f;
    #pragma unroll
    for (int c = 0; c < HD; c += 8) {
        short8_t v = *reinterpret_cast<const short8_t*>(kr + c);
        #pragma unroll
        for (int e = 0; e < 8; ++e) s += bf2f((ushort)v[e]);
    }
    float ph = pf[h];
    E1[idx] = __expf(a1 * ph * s);
    E3[idx] = __expf(a3 * ph * s);
}

// ---------------- V transpose: Vt[b,h,d,j] = V[b,j,h*64+d] ----------------
__global__ __launch_bounds__(256) void transpose_v_kernel(const ushort* __restrict__ Vb,
                                                          ushort* __restrict__ Vt) {
    __shared__ ushort t[64][72];
    int bh = blockIdx.x; int b = bh >> 4, h = bh & 15;
    int j0 = blockIdx.y * 64;
    #pragma unroll
    for (int s = 0; s < 2; ++s) {
        int ch = threadIdx.x + s * 256;
        int row = ch >> 3, c = (ch & 7) * 8;
        *reinterpret_cast<short8_t*>(&t[row][c]) =
            *reinterpret_cast<const short8_t*>(Vb + (size_t)(b * SS + j0 + row) * DD + h * HD + c);
    }
    __syncthreads();
    #pragma unroll
    for (int s = 0; s < 2; ++s) {
        int ch = threadIdx.x + s * 256;
        int drow = ch >> 3, c = (ch & 7) * 8;
        short8_t v;
        #pragma unroll
        for (int e = 0; e < 8; ++e) v[e] = (short)t[c + e][drow];
        *reinterpret_cast<short8_t*>(Vt + (size_t)(bh * HD + drow) * SS + j0 + c) = v;
    }
}

// ---------------- two-pass resonance attention, 32 q-rows/block (2x K/V reuse) ----------------
// R12-validated arithmetic per q-row (absmax 0.0098). Structural change: each block
// serves TWO 16-row q-tiles; every K fragment feeds both tiles' QK MFMAs and every V
// fragment feeds both PV accumulators -> K/V L2 traffic halves (530 -> ~265 MB), the
// resource all previous rounds were pinned on. Grid 2048 -> 1024 blocks.
// Registers: pass A ~90 (lA+lB 32, 4 Q-frags 16), pass B ~80 (caccA+caccB 32) — <=128.
// LDS 69.6 KB (2 blocks/CU). Tripwire: WRITE_SIZE must stay ~4MB (no spill).
__global__ __launch_bounds__(256) void attn_kernel(
    const ushort* __restrict__ Qb, const ushort* __restrict__ Kb,
    const ushort* __restrict__ Vt, const float* __restrict__ E1,
    const float* __restrict__ E3, ushort* __restrict__ ctxb)
{
    __shared__ ushort ycache[4][32][264];  // per-wave bf16 y cache (2 q-tiles); reused as f32 ctx partials
    __shared__ float lbuf[4][4][32];       // [wave][t][qrow 0..31]
    const int wg  = blockIdx.x;
    const int swz = (wg & 7) * 128 + (wg >> 3);   // XCD swizzle (1024 % 8 == 0)
    const int bh  = swz >> 5;
    const int qb  = (swz & 31) * 32;              // 32-row q-block
    const int b = bh >> 4, h = bh & 15;
    const int wave = threadIdx.x >> 6;
    const int lane = threadIdx.x & 63;
    const int fr = lane & 15;
    const int g  = lane >> 4;
    const int fk = g * 8;

    const float wt[4] = {0.008f, 0.032f, 0.16f, 0.8f};   // momentum-collapsed weights

    // Q A-fragments for both 16-row tiles (pre-scaled)
    const ushort* qbase0 = Qb + (size_t)(b * SS + qb + fr) * DD + h * HD;
    const ushort* qbase1 = Qb + (size_t)(b * SS + qb + 16 + fr) * DD + h * HD;
    const short8_t aq0a = *reinterpret_cast<const short8_t*>(qbase0 + fk);
    const short8_t aq1a = *reinterpret_cast<const short8_t*>(qbase0 + 32 + fk);
    const short8_t aq0b = *reinterpret_cast<const short8_t*>(qbase1 + fk);
    const short8_t aq1b = *reinterpret_cast<const short8_t*>(qbase1 + 32 + fk);

    const float* e1h = E1 + bh * SS;
    const float* e3h = E3 + bh * SS;
    const ushort* kcol = Kb + (size_t)b * SS * DD + h * HD;

    // ---- pass A: shared K frags -> both tiles' QK^T + exp2 + l + y-cache ----
    float lA[4][4] = {}, lB[4][4] = {};
    for (int it = 0; it < 4; ++it) {
        const int k0 = wave * 256 + it * 64;
        #pragma unroll
        for (int n = 0; n < 4; ++n) {
            const ushort* kb = kcol + (size_t)(k0 + n * 16 + fr) * DD;
            short8_t bk0 = *reinterpret_cast<const short8_t*>(kb + fk);
            short8_t bk1 = *reinterpret_cast<const short8_t*>(kb + 32 + fk);
            f32x4 za = {0.f, 0.f, 0.f, 0.f};
            f32x4 zb = {0.f, 0.f, 0.f, 0.f};
            za = __builtin_amdgcn_mfma_f32_16x16x32_bf16(aq0a, bk0, za, 0, 0, 0);
            za = __builtin_amdgcn_mfma_f32_16x16x32_bf16(aq1a, bk1, za, 0, 0, 0);
            zb = __builtin_amdgcn_mfma_f32_16x16x32_bf16(aq0b, bk0, zb, 0, 0, 0);
            zb = __builtin_amdgcn_mfma_f32_16x16x32_bf16(aq1b, bk1, zb, 0, 0, 0);
            float e1v = e1h[k0 + n * 16 + fr];
            float e3v = e3h[k0 + n * 16 + fr];
            #pragma unroll
            for (int r = 0; r < 4; ++r) {
                float ya  = EXP2(za[r]);
                float ya2 = ya * ya;
                float ya4 = ya2 * ya2;
                float ya6 = ya4 * ya2;
                lA[0][r] += ya4;
                lA[1][r] += ya4 * ya * e1v;
                lA[2][r] += ya6;
                lA[3][r] += ya6 * ya * e3v;
                ycache[wave][g * 4 + r][it * 64 + n * 16 + fr] = f2bf(ya);
                float yb  = EXP2(zb[r]);
                float yb2 = yb * yb;
                float yb4 = yb2 * yb2;
                float yb6 = yb4 * yb2;
                lB[0][r] += yb4;
                lB[1][r] += yb4 * yb * e1v;
                lB[2][r] += yb6;
                lB[3][r] += yb6 * yb * e3v;
                ycache[wave][16 + g * 4 + r][it * 64 + n * 16 + fr] = f2bf(yb);
            }
        }
    }
    // reduce across the 16 k-col lanes (lane bits 0..3)
    #pragma unroll
    for (int t = 0; t < 4; ++t)
        #pragma unroll
        for (int r = 0; r < 4; ++r) {
            float sa = lA[t][r];
            sa += __shfl_xor(sa, 1);
            sa += __shfl_xor(sa, 2);
            sa += __shfl_xor(sa, 4);
            sa += __shfl_xor(sa, 8);
            lA[t][r] = sa;
            float sb = lB[t][r];
            sb += __shfl_xor(sb, 1);
            sb += __shfl_xor(sb, 2);
            sb += __shfl_xor(sb, 4);
            sb += __shfl_xor(sb, 8);
            lB[t][r] = sb;
        }
    if (fr == 0) {
        #pragma unroll
        for (int t = 0; t < 4; ++t)
            #pragma unroll
            for (int r = 0; r < 4; ++r) {
                lbuf[wave][t][g * 4 + r]      = lA[t][r];
                lbuf[wave][t][16 + g * 4 + r] = lB[t][r];
            }
    }
    __syncthreads();   // orders ycache writes + lbuf for cross-lane pass-B reads

    // per-lane normalized weights for A-frag q-rows fr (tile0) and 16+fr (tile1)
    float wlA[4], wlB[4];
    #pragma unroll
    for (int t = 0; t < 4; ++t) {
        float sa = lbuf[0][t][fr] + lbuf[1][t][fr] + lbuf[2][t][fr] + lbuf[3][t][fr];
        float sb = lbuf[0][t][16 + fr] + lbuf[1][t][16 + fr] + lbuf[2][t][16 + fr] + lbuf[3][t][16 + fr];
        wlA[t] = wt[t] / sa;
        wlB[t] = wt[t] / sb;
    }

    // ---- pass B: shared V frags -> both tiles' normalized P + PV ----
    f32x4 caccA[4] = {}, caccB[4] = {};
    union FragU { short8_t s; unsigned u[4]; };
    for (int it = 0; it < 4; ++it) {
        const int k0 = wave * 256 + it * 64;
        #pragma unroll
        for (int half = 0; half < 2; ++half) {
            short8_t ya8 = *reinterpret_cast<const short8_t*>(
                &ycache[wave][fr][it * 64 + half * 32 + fk]);
            short8_t yb8 = *reinterpret_cast<const short8_t*>(
                &ycache[wave][16 + fr][it * 64 + half * 32 + fk]);
            const float* e1p = e1h + k0 + half * 32 + fk;
            const float* e3p = e3h + k0 + half * 32 + fk;
            float4 e1a = *reinterpret_cast<const float4*>(e1p);
            float4 e1b = *reinterpret_cast<const float4*>(e1p + 4);
            float4 e3a = *reinterpret_cast<const float4*>(e3p);
            float4 e3b = *reinterpret_cast<const float4*>(e3p + 4);
            FragU paA, paB;
            #pragma unroll
            for (int i = 0; i < 4; ++i) {
                float pva[2], pvb[2];
                #pragma unroll
                for (int j = 0; j < 2; ++j) {
                    const int e = 2 * i + j;
                    float e1v = (e < 4) ? ((const float*)&e1a)[e] : ((const float*)&e1b)[e - 4];
                    float e3v = (e < 4) ? ((const float*)&e3a)[e] : ((const float*)&e3b)[e - 4];
                    float ya  = bf2f((ushort)ya8[e]);
                    float ya2 = ya * ya;
                    float ya4 = ya2 * ya2;
                    float t1a = fmaf(ya, wlA[1] * e1v, wlA[0]);
                    float t2a = fmaf(ya, wlA[3] * e3v, wlA[2]);
                    pva[j] = ya4 * fmaf(ya2, t2a, t1a);
                    float yb  = bf2f((ushort)yb8[e]);
                    float yb2 = yb * yb;
                    float yb4 = yb2 * yb2;
                    float t1b = fmaf(yb, wlB[1] * e1v, wlB[0]);
                    float t2b = fmaf(yb, wlB[3] * e3v, wlB[2]);
                    pvb[j] = yb4 * fmaf(yb2, t2b, t1b);
                }
                paA.u[i] = pkbf(pva[0], pva[1]);
                paB.u[i] = pkbf(pvb[0], pvb[1]);
            }
            #pragma unroll
            for (int n2 = 0; n2 < 4; ++n2) {
                const ushort* vb = Vt + (size_t)(bh * HD + n2 * 16 + fr) * SS + k0 + half * 32;
                short8_t v = *reinterpret_cast<const short8_t*>(vb + fk);
                caccA[n2] = __builtin_amdgcn_mfma_f32_16x16x32_bf16(paA.s, v, caccA[n2], 0, 0, 0);
                caccB[n2] = __builtin_amdgcn_mfma_f32_16x16x32_bf16(paB.s, v, caccB[n2], 0, 0, 0);
            }
        }
    }

    // ---- epilogue: per-wave partials -> cross-wave sum, both tiles ----
    __syncthreads();   // all ycache reads done; safe to reuse as f32
    float* ctxp = (float*)&ycache[wave][0][0];   // [32][68] f32 view (8704B <= 16896B region)
    #pragma unroll
    for (int n2 = 0; n2 < 4; ++n2)
        #pragma unroll
        for (int q = 0; q < 4; ++q) {
            ctxp[(g * 4 + q) * 68 + n2 * 16 + fr]        = caccA[n2][q];
            ctxp[(16 + g * 4 + q) * 68 + n2 * 16 + fr]   = caccB[n2][q];
        }
    __syncthreads();

    const int d0 = (threadIdx.x & 15) * 4;
    float* base = (float*)&ycache[0][0][0];      // wave stride = 4224 f32
    #pragma unroll
    for (int rr = 0; rr < 2; ++rr) {
        int row = rr * 16 + (threadIdx.x >> 4);
        float4 s0 = *reinterpret_cast<float4*>(base + 0 * 4224 + row * 68 + d0);
        float4 s1 = *reinterpret_cast<float4*>(base + 1 * 4224 + row * 68 + d0);
        float4 s2 = *reinterpret_cast<float4*>(base + 2 * 4224 + row * 68 + d0);
        float4 s3 = *reinterpret_cast<float4*>(base + 3 * 4224 + row * 68 + d0);
        float ox = s0.x + s1.x + s2.x + s3.x;
        float oy = s0.y + s1.y + s2.y + s3.y;
        float oz = s0.z + s1.z + s2.z + s3.z;
        float ow = s0.w + s1.w + s2.w + s3.w;
        uint2 o;
        o.x = pkbf(ox, oy);
        o.y = pkbf(oz, ow);
        size_t off = (size_t)(b * SS + qb + row) * DD + h * HD + d0;
        *reinterpret_cast<uint2*>(ctxb + off) = o;
    }
}

// ---------------- launch ----------------
extern "C" void kernel_launch(void* const* d_in, const int* in_sizes, int n_in,
                              void* d_out, int out_size, void* d_ws, size_t ws_size,
                              hipStream_t stream) {
    const float* x  = (const float*)d_in[0];
    const float* Wq = (const float*)d_in[1];
    const float* bq = (const float*)d_in[2];
    const float* Wk = (const float*)d_in[3];
    const float* bk = (const float*)d_in[4];
    const float* Wv = (const float*)d_in[5];
    const float* bv = (const float*)d_in[6];
    const float* Wo = (const float*)d_in[7];
    const float* bo = (const float*)d_in[8];
    // d_in[9] resonance_bias: per-head row-constant -> cancels in softmax
    const float* pf = (const float*)d_in[10];

    // workspace layout (~32.3 MB)
    ushort* xb   = (ushort*)d_ws;
    ushort* wqb  = xb  + (size_t)2 * 1024 * 1024;
    ushort* wkb  = wqb + (size_t)1024 * 1024;
    ushort* wvb  = wkb + (size_t)1024 * 1024;
    ushort* wob  = wvb + (size_t)1024 * 1024;
    ushort* Qb   = wob + (size_t)1024 * 1024;
    ushort* Kb   = Qb  + (size_t)2 * 1024 * 1024;
    ushort* Vb   = Kb  + (size_t)2 * 1024 * 1024;
    ushort* Vt   = Vb  + (size_t)2 * 1024 * 1024;
    ushort* ctxb = Vt  + (size_t)2 * 1024 * 1024;
    float*  E1p  = (float*)(ctxb + (size_t)2 * 1024 * 1024);
    float*  E3p  = E1p + (size_t)BH * SS;

    // per-iteration constants (match reference f32 casting)
    float ph[4], ctv[4];
    for (int t = 0; t < 4; ++t) {
        double tn = (double)t / 4.0;
        ph[t]  = sinf((float)(2.0 * tn * M_PI + 0.0));
        ctv[t] = (float)((0.8 + 0.2 * (double)t) * 0.125);  // beta_t / sqrt(HD)
    }
    const double LOG2E = 1.44269504088896340736;
    float qscale = (float)(0.025 * LOG2E);  // Q pre-scale: S' = 0.025*log2e*S
    float a1 = ctv[1] * ph[1];   // c1 * sin(pi/2)
    float a3 = ctv[3] * ph[3];   // c3 * sin(3pi/2)

    cvt_all_kernel<<<6144, 256, 0, stream>>>(x, Wq, Wk, Wv, Wo, xb, wqb, wkb, wvb, wob);

    gemm_qkv_kernel<<<dim3(8, 16, 3), 256, 0, stream>>>(xb, wqb, wkb, wvb, bq, bk, bv,
                                                        Qb, Kb, Vb, qscale);

    tables_kernel<<<BH * SS / 256, 256, 0, stream>>>(Kb, pf, E1p, E3p, a1, a3);
    transpose_v_kernel<<<dim3(BH, SS / 64), 256, 0, stream>>>(Vb, Vt);

    attn_kernel<<<1024, 256, 0, stream>>>(Qb, Kb, Vt, E1p, E3p, ctxb);

    gemm_out_kernel<<<dim3(8, 32), 256, 0, stream>>>(ctxb, wob, bo, (float*)d_out);
}

// Round 14
// 109.223 us; speedup vs baseline: 1.4231x; 1.0215x over previous
//
#include <hip/hip_runtime.h>
#include <hip/hip_bf16.h>
#include <math.h>

#define BB 2
#define SS 1024
#define DD 1024
#define HH 16
#define HD 64
#define BH (BB*HH)

typedef __attribute__((ext_vector_type(8))) short short8_t;
typedef __attribute__((ext_vector_type(4))) float f32x4;

#if __has_builtin(__builtin_amdgcn_exp2f)
#define EXP2(x) __builtin_amdgcn_exp2f(x)
#else
#define EXP2(x) exp2f(x)
#endif

__device__ __forceinline__ ushort f2bf(float f) {
    union { float f; unsigned u; } a; a.f = f;
    unsigned u = a.u;
    u += 0x7FFFu + ((u >> 16) & 1u);   // RNE
    return (ushort)(u >> 16);
}
__device__ __forceinline__ float bf2f(ushort b) {
    union { unsigned u; float f; } a; a.u = ((unsigned)b) << 16;
    return a.f;
}
// packed f32x2 -> bf16x2 (RNE), low = a
__device__ __forceinline__ unsigned pkbf(float a, float b) {
    unsigned r;
    asm("v_cvt_pk_bf16_f32 %0, %1, %2" : "=v"(r) : "v"(a), "v"(b));
    return r;
}

// ---------------- fp32 -> bf16 conversion, all 5 tensors in one launch ----------------
__global__ __launch_bounds__(256) void cvt_all_kernel(
    const float* __restrict__ x,  const float* __restrict__ wq,
    const float* __restrict__ wk, const float* __restrict__ wv,
    const float* __restrict__ wo,
    ushort* __restrict__ xb,  ushort* __restrict__ wqb, ushort* __restrict__ wkb,
    ushort* __restrict__ wvb, ushort* __restrict__ wob)
{
    int bid = blockIdx.x;
    const float* src; ushort* dst; int off;
    if (bid < 2048) { src = x; dst = xb; off = bid; }
    else {
        int seg = (bid - 2048) >> 10;
        off = (bid - 2048) & 1023;
        if (seg == 0)      { src = wq; dst = wqb; }
        else if (seg == 1) { src = wk; dst = wkb; }
        else if (seg == 2) { src = wv; dst = wvb; }
        else               { src = wo; dst = wob; }
    }
    int i = (off * 256 + threadIdx.x) * 4;
    float4 v = *reinterpret_cast<const float4*>(src + i);
    ushort4 o;
    o.x = f2bf(v.x); o.y = f2bf(v.y); o.z = f2bf(v.z); o.w = f2bf(v.w);
    *reinterpret_cast<ushort4*>(dst + i) = o;
}

// ---------------- bf16 GEMM (m97 structure): C = A[M,K]*B[N,K]^T, global_load_lds ----------------
template<int BM, int OUT_F32>
__device__ __forceinline__ void gemm_body(
    const ushort* __restrict__ A, const ushort* __restrict__ Bm,
    const float* __restrict__ bias, void* __restrict__ Cout,
    int N, int K, float scale)
{
    constexpr int BK = 32;
    __shared__ ushort lsa[BM * BK];
    __shared__ ushort lsb[128 * BK];
    const int tid  = threadIdx.x;
    const int lane = tid & 63;
    const int wave = tid >> 6;
    constexpr int RI = BM / 32;
    const int wrow = (wave >> 1) * (BM / 2);
    const int wcol = (wave & 1) * 64;
    const int tileM = blockIdx.y * BM;
    const int tileN = blockIdx.x * 128;
    const int fr  = lane & 15;
    const int fks = (lane >> 4) * 8;
    const int l4  = lane >> 2;        // row within 16-row chunk
    const int lm4 = lane & 3;         // 16B slot within 64B row
    f32x4 acc[RI][4] = {};

    for (int kb = 0; kb < K; kb += BK) {
        __syncthreads();
        #pragma unroll
        for (int i = 0; i < BM / 64; ++i) {
            int chunk = wave * (BM / 64) + i;
            const ushort* g = A + (size_t)(tileM + chunk * 16 + l4) * K + kb + lm4 * 8;
            __builtin_amdgcn_global_load_lds(
                (const __attribute__((address_space(1))) unsigned*)g,
                (__attribute__((address_space(3))) unsigned*)&lsa[chunk * 512], 16, 0, 0);
        }
        #pragma unroll
        for (int i = 0; i < 2; ++i) {
            int chunk = wave * 2 + i;
            const ushort* g = Bm + (size_t)(tileN + chunk * 16 + l4) * K + kb + lm4 * 8;
            __builtin_amdgcn_global_load_lds(
                (const __attribute__((address_space(1))) unsigned*)g,
                (__attribute__((address_space(3))) unsigned*)&lsb[chunk * 512], 16, 0, 0);
        }
        __syncthreads();
        short8_t af[RI], bfg[4];
        #pragma unroll
        for (int r = 0; r < RI; ++r)
            af[r] = *reinterpret_cast<const short8_t*>(&lsa[(wrow + r * 16 + fr) * BK + fks]);
        #pragma unroll
        for (int c = 0; c < 4; ++c)
            bfg[c] = *reinterpret_cast<const short8_t*>(&lsb[(wcol + c * 16 + fr) * BK + fks]);
        #pragma unroll
        for (int r = 0; r < RI; ++r)
            #pragma unroll
            for (int c = 0; c < 4; ++c)
                acc[r][c] = __builtin_amdgcn_mfma_f32_16x16x32_bf16(af[r], bfg[c], acc[r][c], 0, 0, 0);
    }

    const int rr = (lane >> 4) * 4;
    #pragma unroll
    for (int r = 0; r < RI; ++r) {
        #pragma unroll
        for (int c = 0; c < 4; ++c) {
            int n = tileN + wcol + c * 16 + fr;
            float bv = bias[n];
            #pragma unroll
            for (int q = 0; q < 4; ++q) {
                int m = tileM + wrow + r * 16 + rr + q;
                float v = (acc[r][c][q] + bv) * scale;
                if (OUT_F32) ((float*)Cout)[(size_t)m * N + n] = v;
                else         ((ushort*)Cout)[(size_t)m * N + n] = f2bf(v);
            }
        }
    }
}

__global__ __launch_bounds__(256) void gemm_qkv_kernel(
    const ushort* __restrict__ xb,
    const ushort* __restrict__ wq, const ushort* __restrict__ wk, const ushort* __restrict__ wv,
    const float* __restrict__ bq, const float* __restrict__ bk, const float* __restrict__ bv,
    ushort* __restrict__ Qb, ushort* __restrict__ Kb, ushort* __restrict__ Vb, float qscale)
{
    const ushort* Bm; const float* bias; ushort* out; float sc;
    if (blockIdx.z == 0)      { Bm = wq; bias = bq; out = Qb; sc = qscale; }
    else if (blockIdx.z == 1) { Bm = wk; bias = bk; out = Kb; sc = 1.0f; }
    else                      { Bm = wv; bias = bv; out = Vb; sc = 1.0f; }
    gemm_body<128, 0>(xb, Bm, bias, out, DD, DD, sc);
}

__global__ __launch_bounds__(256) void gemm_out_kernel(
    const ushort* __restrict__ ctxb, const ushort* __restrict__ wo,
    const float* __restrict__ bo, float* __restrict__ out)
{
    gemm_body<64, 1>(ctxb, wo, bo, out, DD, DD, 1.0f);
}

// ---------------- tables + head-major K repack ----------------
// E_t[bh,j] = exp(c_t*ph_t*pf[h]*rk[bh,j]) for t=1,3;  Kh[bh][j][d] = Kb[b][j][h*64+d]
// (Kh rows are 128B contiguous -> attn's K subtile reads become 2KB sequential,
//  avoiding the 2KB-stride L2 channel aliasing.)
__global__ __launch_bounds__(256) void tables_kernel(const ushort* __restrict__ Kb,
                                                     const float* __restrict__ pf,
                                                     float* __restrict__ E1, float* __restrict__ E3,
                                                     ushort* __restrict__ Kh,
                                                     float a1, float a3) {
    int idx = blockIdx.x * blockDim.x + threadIdx.x;  // [0, BH*SS)
    int j  = idx & (SS - 1);
    int bh = idx >> 10;
    int b = bh >> 4, h = bh & 15;
    const ushort* kr = Kb + (size_t)(b * SS + j) * DD + h * HD;
    ushort* kout = Kh + (size_t)idx * HD;
    float s = 0.f;
    #pragma unroll
    for (int c = 0; c < HD; c += 8) {
        short8_t v = *reinterpret_cast<const short8_t*>(kr + c);
        *reinterpret_cast<short8_t*>(kout + c) = v;
        #pragma unroll
        for (int e = 0; e < 8; ++e) s += bf2f((ushort)v[e]);
    }
    float ph = pf[h];
    E1[idx] = __expf(a1 * ph * s);
    E3[idx] = __expf(a3 * ph * s);
}

// ---------------- V transpose, k-tiled: Vt2[bh][j/32][d][j%32] = V[b,j,h*64+d] ----------------
// Each 4KB tile holds 64 d-rows x 32 k; a PV fragment read (16 d-rows x 64B) is
// 1KB contiguous instead of 16 lines at 2KB stride.
__global__ __launch_bounds__(256) void transpose_v_kernel(const ushort* __restrict__ Vb,
                                                          ushort* __restrict__ Vt2) {
    __shared__ ushort t[64][72];
    int bh = blockIdx.x; int b = bh >> 4, h = bh & 15;
    int j0 = blockIdx.y * 64;
    #pragma unroll
    for (int s = 0; s < 2; ++s) {
        int ch = threadIdx.x + s * 256;
        int row = ch >> 3, c = (ch & 7) * 8;
        *reinterpret_cast<short8_t*>(&t[row][c]) =
            *reinterpret_cast<const short8_t*>(Vb + (size_t)(b * SS + j0 + row) * DD + h * HD + c);
    }
    __syncthreads();
    #pragma unroll
    for (int s = 0; s < 2; ++s) {
        int ch = threadIdx.x + s * 256;
        int drow = ch >> 3, c = (ch & 7) * 8;
        short8_t v;
        #pragma unroll
        for (int e = 0; e < 8; ++e) v[e] = (short)t[c + e][drow];
        int kb32 = (j0 + c) >> 5;
        int kk   = c & 31;
        *reinterpret_cast<short8_t*>(
            Vt2 + ((size_t)(bh * (SS / 32) + kb32) * HD + drow) * 32 + kk) = v;
    }
}

// ---------------- two-pass resonance attention, 32 q-rows/block, contiguous K/V ----------------
// R13-validated arithmetic (absmax 0.0098); ONLY the K/V address computations changed
// to the repacked layouts (Kh head-major, Vt2 k-tiled) so every wave request stream is
// sequential. Tripwire: WRITE_SIZE must stay ~4MB (no spill).
__global__ __launch_bounds__(256) void attn_kernel(
    const ushort* __restrict__ Qb, const ushort* __restrict__ Kh,
    const ushort* __restrict__ Vt2, const float* __restrict__ E1,
    const float* __restrict__ E3, ushort* __restrict__ ctxb)
{
    __shared__ ushort ycache[4][32][264];  // per-wave bf16 y cache (2 q-tiles); reused as f32 ctx partials
    __shared__ float lbuf[4][4][32];       // [wave][t][qrow 0..31]
    const int wg  = blockIdx.x;
    const int swz = (wg & 7) * 128 + (wg >> 3);   // XCD swizzle (1024 % 8 == 0)
    const int bh  = swz >> 5;
    const int qb  = (swz & 31) * 32;              // 32-row q-block
    const int b = bh >> 4, h = bh & 15;
    const int wave = threadIdx.x >> 6;
    const int lane = threadIdx.x & 63;
    const int fr = lane & 15;
    const int g  = lane >> 4;
    const int fk = g * 8;

    const float wt[4] = {0.008f, 0.032f, 0.16f, 0.8f};   // momentum-collapsed weights

    // Q A-fragments for both 16-row tiles (pre-scaled)
    const ushort* qbase0 = Qb + (size_t)(b * SS + qb + fr) * DD + h * HD;
    const ushort* qbase1 = Qb + (size_t)(b * SS + qb + 16 + fr) * DD + h * HD;
    const short8_t aq0a = *reinterpret_cast<const short8_t*>(qbase0 + fk);
    const short8_t aq1a = *reinterpret_cast<const short8_t*>(qbase0 + 32 + fk);
    const short8_t aq0b = *reinterpret_cast<const short8_t*>(qbase1 + fk);
    const short8_t aq1b = *reinterpret_cast<const short8_t*>(qbase1 + 32 + fk);

    const float* e1h = E1 + bh * SS;
    const float* e3h = E3 + bh * SS;
    const ushort* khead = Kh + (size_t)bh * SS * HD;
    const ushort* vhead = Vt2 + (size_t)bh * (SS / 32) * HD * 32;

    // ---- pass A: shared K frags -> both tiles' QK^T + exp2 + l + y-cache ----
    float lA[4][4] = {}, lB[4][4] = {};
    for (int it = 0; it < 4; ++it) {
        const int k0 = wave * 256 + it * 64;
        #pragma unroll
        for (int n = 0; n < 4; ++n) {
            const ushort* kb = khead + (size_t)(k0 + n * 16 + fr) * HD;
            short8_t bk0 = *reinterpret_cast<const short8_t*>(kb + fk);
            short8_t bk1 = *reinterpret_cast<const short8_t*>(kb + 32 + fk);
            f32x4 za = {0.f, 0.f, 0.f, 0.f};
            f32x4 zb = {0.f, 0.f, 0.f, 0.f};
            za = __builtin_amdgcn_mfma_f32_16x16x32_bf16(aq0a, bk0, za, 0, 0, 0);
            za = __builtin_amdgcn_mfma_f32_16x16x32_bf16(aq1a, bk1, za, 0, 0, 0);
            zb = __builtin_amdgcn_mfma_f32_16x16x32_bf16(aq0b, bk0, zb, 0, 0, 0);
            zb = __builtin_amdgcn_mfma_f32_16x16x32_bf16(aq1b, bk1, zb, 0, 0, 0);
            float e1v = e1h[k0 + n * 16 + fr];
            float e3v = e3h[k0 + n * 16 + fr];
            #pragma unroll
            for (int r = 0; r < 4; ++r) {
                float ya  = EXP2(za[r]);
                float ya2 = ya * ya;
                float ya4 = ya2 * ya2;
                float ya6 = ya4 * ya2;
                lA[0][r] += ya4;
                lA[1][r] += ya4 * ya * e1v;
                lA[2][r] += ya6;
                lA[3][r] += ya6 * ya * e3v;
                ycache[wave][g * 4 + r][it * 64 + n * 16 + fr] = f2bf(ya);
                float yb  = EXP2(zb[r]);
                float yb2 = yb * yb;
                float yb4 = yb2 * yb2;
                float yb6 = yb4 * yb2;
                lB[0][r] += yb4;
                lB[1][r] += yb4 * yb * e1v;
                lB[2][r] += yb6;
                lB[3][r] += yb6 * yb * e3v;
                ycache[wave][16 + g * 4 + r][it * 64 + n * 16 + fr] = f2bf(yb);
            }
        }
    }
    // reduce across the 16 k-col lanes (lane bits 0..3)
    #pragma unroll
    for (int t = 0; t < 4; ++t)
        #pragma unroll
        for (int r = 0; r < 4; ++r) {
            float sa = lA[t][r];
            sa += __shfl_xor(sa, 1);
            sa += __shfl_xor(sa, 2);
            sa += __shfl_xor(sa, 4);
            sa += __shfl_xor(sa, 8);
            lA[t][r] = sa;
            float sb = lB[t][r];
            sb += __shfl_xor(sb, 1);
            sb += __shfl_xor(sb, 2);
            sb += __shfl_xor(sb, 4);
            sb += __shfl_xor(sb, 8);
            lB[t][r] = sb;
        }
    if (fr == 0) {
        #pragma unroll
        for (int t = 0; t < 4; ++t)
            #pragma unroll
            for (int r = 0; r < 4; ++r) {
                lbuf[wave][t][g * 4 + r]      = lA[t][r];
                lbuf[wave][t][16 + g * 4 + r] = lB[t][r];
            }
    }
    __syncthreads();   // orders ycache writes + lbuf for cross-lane pass-B reads

    // per-lane normalized weights for A-frag q-rows fr (tile0) and 16+fr (tile1)
    float wlA[4], wlB[4];
    #pragma unroll
    for (int t = 0; t < 4; ++t) {
        float sa = lbuf[0][t][fr] + lbuf[1][t][fr] + lbuf[2][t][fr] + lbuf[3][t][fr];
        float sb = lbuf[0][t][16 + fr] + lbuf[1][t][16 + fr] + lbuf[2][t][16 + fr] + lbuf[3][t][16 + fr];
        wlA[t] = wt[t] / sa;
        wlB[t] = wt[t] / sb;
    }

    // ---- pass B: shared V frags -> both tiles' normalized P + PV ----
    f32x4 caccA[4] = {}, caccB[4] = {};
    union FragU { short8_t s; unsigned u[4]; };
    for (int it = 0; it < 4; ++it) {
        const int k0 = wave * 256 + it * 64;
        #pragma unroll
        for (int half = 0; half < 2; ++half) {
            short8_t ya8 = *reinterpret_cast<const short8_t*>(
                &ycache[wave][fr][it * 64 + half * 32 + fk]);
            short8_t yb8 = *reinterpret_cast<const short8_t*>(
                &ycache[wave][16 + fr][it * 64 + half * 32 + fk]);
            const float* e1p = e1h + k0 + half * 32 + fk;
            const float* e3p = e3h + k0 + half * 32 + fk;
            float4 e1a = *reinterpret_cast<const float4*>(e1p);
            float4 e1b = *reinterpret_cast<const float4*>(e1p + 4);
            float4 e3a = *reinterpret_cast<const float4*>(e3p);
            float4 e3b = *reinterpret_cast<const float4*>(e3p + 4);
            FragU paA, paB;
            #pragma unroll
            for (int i = 0; i < 4; ++i) {
                float pva[2], pvb[2];
                #pragma unroll
                for (int j = 0; j < 2; ++j) {
                    const int e = 2 * i + j;
                    float e1v = (e < 4) ? ((const float*)&e1a)[e] : ((const float*)&e1b)[e - 4];
                    float e3v = (e < 4) ? ((const float*)&e3a)[e] : ((const float*)&e3b)[e - 4];
                    float ya  = bf2f((ushort)ya8[e]);
                    float ya2 = ya * ya;
                    float ya4 = ya2 * ya2;
                    float t1a = fmaf(ya, wlA[1] * e1v, wlA[0]);
                    float t2a = fmaf(ya, wlA[3] * e3v, wlA[2]);
                    pva[j] = ya4 * fmaf(ya2, t2a, t1a);
                    float yb  = bf2f((ushort)yb8[e]);
                    float yb2 = yb * yb;
                    float yb4 = yb2 * yb2;
                    float t1b = fmaf(yb, wlB[1] * e1v, wlB[0]);
                    float t2b = fmaf(yb, wlB[3] * e3v, wlB[2]);
                    pvb[j] = yb4 * fmaf(yb2, t2b, t1b);
                }
                paA.u[i] = pkbf(pva[0], pva[1]);
                paB.u[i] = pkbf(pvb[0], pvb[1]);
            }
            const ushort* vt = vhead + (size_t)((k0 + half * 32) >> 5) * HD * 32;
            #pragma unroll
            for (int n2 = 0; n2 < 4; ++n2) {
                short8_t v = *reinterpret_cast<const short8_t*>(
                    vt + (n2 * 16 + fr) * 32 + fk);
                caccA[n2] = __builtin_amdgcn_mfma_f32_16x16x32_bf16(paA.s, v, caccA[n2], 0, 0, 0);
                caccB[n2] = __builtin_amdgcn_mfma_f32_16x16x32_bf16(paB.s, v, caccB[n2], 0, 0, 0);
            }
        }
    }

    // ---- epilogue: per-wave partials -> cross-wave sum, both tiles ----
    __syncthreads();   // all ycache reads done; safe to reuse as f32
    float* ctxp = (float*)&ycache[wave][0][0];   // [32][68] f32 view (8704B <= 16896B region)
    #pragma unroll
    for (int n2 = 0; n2 < 4; ++n2)
        #pragma unroll
        for (int q = 0; q < 4; ++q) {
            ctxp[(g * 4 + q) * 68 + n2 * 16 + fr]        = caccA[n2][q];
            ctxp[(16 + g * 4 + q) * 68 + n2 * 16 + fr]   = caccB[n2][q];
        }
    __syncthreads();

    const int d0 = (threadIdx.x & 15) * 4;
    float* base = (float*)&ycache[0][0][0];      // wave stride = 4224 f32
    #pragma unroll
    for (int rr = 0; rr < 2; ++rr) {
        int row = rr * 16 + (threadIdx.x >> 4);
        float4 s0 = *reinterpret_cast<float4*>(base + 0 * 4224 + row * 68 + d0);
        float4 s1 = *reinterpret_cast<float4*>(base + 1 * 4224 + row * 68 + d0);
        float4 s2 = *reinterpret_cast<float4*>(base + 2 * 4224 + row * 68 + d0);
        float4 s3 = *reinterpret_cast<float4*>(base + 3 * 4224 + row * 68 + d0);
        float ox = s0.x + s1.x + s2.x + s3.x;
        float oy = s0.y + s1.y + s2.y + s3.y;
        float oz = s0.z + s1.z + s2.z + s3.z;
        float ow = s0.w + s1.w + s2.w + s3.w;
        uint2 o;
        o.x = pkbf(ox, oy);
        o.y = pkbf(oz, ow);
        size_t off = (size_t)(b * SS + qb + row) * DD + h * HD + d0;
        *reinterpret_cast<uint2*>(ctxb + off) = o;
    }
}

// ---------------- launch ----------------
extern "C" void kernel_launch(void* const* d_in, const int* in_sizes, int n_in,
                              void* d_out, int out_size, void* d_ws, size_t ws_size,
                              hipStream_t stream) {
    const float* x  = (const float*)d_in[0];
    const float* Wq = (const float*)d_in[1];
    const float* bq = (const float*)d_in[2];
    const float* Wk = (const float*)d_in[3];
    const float* bk = (const float*)d_in[4];
    const float* Wv = (const float*)d_in[5];
    const float* bv = (const float*)d_in[6];
    const float* Wo = (const float*)d_in[7];
    const float* bo = (const float*)d_in[8];
    // d_in[9] resonance_bias: per-head row-constant -> cancels in softmax
    const float* pf = (const float*)d_in[10];

    // workspace layout (~32.3 MB); Kh reuses xb (dead after gemm_qkv)
    ushort* xb   = (ushort*)d_ws;
    ushort* wqb  = xb  + (size_t)2 * 1024 * 1024;
    ushort* wkb  = wqb + (size_t)1024 * 1024;
    ushort* wvb  = wkb + (size_t)1024 * 1024;
    ushort* wob  = wvb + (size_t)1024 * 1024;
    ushort* Qb   = wob + (size_t)1024 * 1024;
    ushort* Kb   = Qb  + (size_t)2 * 1024 * 1024;
    ushort* Vb   = Kb  + (size_t)2 * 1024 * 1024;
    ushort* Vt2  = Vb  + (size_t)2 * 1024 * 1024;
    ushort* ctxb = Vt2 + (size_t)2 * 1024 * 1024;
    float*  E1p  = (float*)(ctxb + (size_t)2 * 1024 * 1024);
    float*  E3p  = E1p + (size_t)BH * SS;
    ushort* Kh   = xb;   // head-major K repack, aliases xb

    // per-iteration constants (match reference f32 casting)
    float ph[4], ctv[4];
    for (int t = 0; t < 4; ++t) {
        double tn = (double)t / 4.0;
        ph[t]  = sinf((float)(2.0 * tn * M_PI + 0.0));
        ctv[t] = (float)((0.8 + 0.2 * (double)t) * 0.125);  // beta_t / sqrt(HD)
    }
    const double LOG2E = 1.44269504088896340736;
    float qscale = (float)(0.025 * LOG2E);  // Q pre-scale: S' = 0.025*log2e*S
    float a1 = ctv[1] * ph[1];   // c1 * sin(pi/2)
    float a3 = ctv[3] * ph[3];   // c3 * sin(3pi/2)

    cvt_all_kernel<<<6144, 256, 0, stream>>>(x, Wq, Wk, Wv, Wo, xb, wqb, wkb, wvb, wob);

    gemm_qkv_kernel<<<dim3(8, 16, 3), 256, 0, stream>>>(xb, wqb, wkb, wvb, bq, bk, bv,
                                                        Qb, Kb, Vb, qscale);

    tables_kernel<<<BH * SS / 256, 256, 0, stream>>>(Kb, pf, E1p, E3p, Kh, a1, a3);
    transpose_v_kernel<<<dim3(BH, SS / 64), 256, 0, stream>>>(Vb, Vt2);

    attn_kernel<<<1024, 256, 0, stream>>>(Qb, Kh, Vt2, E1p, E3p, ctxb);

    gemm_out_kernel<<<dim3(8, 32), 256, 0, stream>>>(ctxb, wob, bo, (float*)d_out);
}